// Round 1
// baseline (371.872 us; speedup 1.0000x reference)
//
#include <hip/hip_runtime.h>
#include <cstdint>
#include <cstddef>

#define B_SZ   8
#define SEQ    4096
#define HID    1024
#define NCH    8          // time chunks
#define CHUNK  512        // SEQ / NCH
#define WARM   320        // warm-up steps (multiple of 16)
#define JTAP   16         // truncated SSM impulse-response taps

// ws layout (bytes)
#define UOFF   0                        // uint32 ucnt[B_SZ*SEQ]      = 128 KB
#define YOFF   (131072)                 // float  y[B_SZ*SEQ]         = 128 KB
#define WOFF   (262144)                 // float  w[JTAP]             (padded)
#define SOFF   (262656)                 // u64    spk[B_SZ*16*SEQ]    = 4 MB

__device__ __forceinline__ void snn_step(float& v, float& r, float xv, bool& s) {
  // match reference rounding: separate mul + add (no FMA contraction)
  v = __fadd_rn(__fmul_rn(v, 0.9f), xv);
  s = (r <= 0.0f) && (v >= 1.0f);
  v = s ? 0.0f : v;
  r = s ? 5.0f : fmaxf(r - 1.0f, 0.0f);
}

// Phase 1: LIF neuron scan, chunked in time with warm-up.
// grid = (HID/256, B_SZ, NCH), block = 256
__global__ __launch_bounds__(256) void snn_kernel(const float* __restrict__ x,
                                                  unsigned long long* __restrict__ spk,
                                                  unsigned int* __restrict__ ucnt) {
  const int hid  = blockIdx.x * 256 + threadIdx.x;
  const int b    = blockIdx.y;
  const int c    = blockIdx.z;
  const int lane = threadIdx.x & 63;
  const int wv   = hid >> 6;                 // global wave-of-hid index 0..15
  const int t0   = c * CHUNK;
  const int t1   = t0 + CHUNK;
  const int tw   = (t0 >= WARM) ? (t0 - WARM) : 0;   // c==0 -> no warm-up, exact
  const float* __restrict__ xp = x + (size_t)(b * SEQ) * HID + hid;

  float v = 0.0f, r = 0.0f;

  // warm-up (no writes) — converges (v,r) to the true chunk-entry state
  for (int t = tw; t < t0; t += 16) {
    float xb[16];
    #pragma unroll
    for (int k = 0; k < 16; ++k) xb[k] = xp[(size_t)(t + k) * HID];
    #pragma unroll
    for (int k = 0; k < 16; ++k) { bool s; snn_step(v, r, xb[k], s); }
  }

  unsigned long long* __restrict__ sp = spk + (size_t)(b * 16 + wv) * SEQ;
  unsigned int* __restrict__ up = ucnt + b * SEQ;

  for (int t = t0; t < t1; t += 16) {
    float xb[16];
    #pragma unroll
    for (int k = 0; k < 16; ++k) xb[k] = xp[(size_t)(t + k) * HID];
    #pragma unroll
    for (int k = 0; k < 16; ++k) {
      bool s; snn_step(v, r, xb[k], s);
      unsigned long long m = __ballot(s);
      if (lane == 0) {
        sp[t + k] = m;                                    // bit-packed spikes
        atomicAdd(&up[t + k], (unsigned int)__popcll(m)); // exact spike count
      }
    }
  }
}

// Phase 0 (independent of phase 1): w_m = C . A^m . B  via Krylov iteration.
// 1 block, 64 threads (one wave).
__global__ void w_kernel(const float* __restrict__ A, const float* __restrict__ Bv,
                         const float* __restrict__ Cv, float* __restrict__ w) {
  const int lane = threadIdx.x;  // 0..63
  float arow[64];
  #pragma unroll 8
  for (int s = 0; s < 64; ++s) arow[s] = A[lane * 64 + s];
  float p = Bv[lane];
  float cv = Cv[lane];
  for (int m = 0; m < JTAP; ++m) {
    float t = cv * p;
    #pragma unroll
    for (int off = 32; off; off >>= 1) t += __shfl_xor(t, off);
    if (lane == 0) w[m] = t;
    float np = 0.0f;
    #pragma unroll 8
    for (int s = 0; s < 64; ++s) np = fmaf(arow[s], __shfl(p, s), np);
    p = np;
  }
}

// Phase 2: y[b][t] = D*u_t + sum_{m<JTAP} w_m * u_{t-m}
__global__ __launch_bounds__(256) void y_kernel(const unsigned int* __restrict__ ucnt,
                                                const float* __restrict__ w,
                                                const float* __restrict__ Dp,
                                                float* __restrict__ y) {
  const int i = blockIdx.x * 256 + threadIdx.x;   // 0..B_SZ*SEQ-1
  const int b = i >> 12;
  const int t = i & (SEQ - 1);
  const unsigned int* __restrict__ up = ucnt + b * SEQ;
  const float D = Dp[0];
  float acc = D * (up[t] * (1.0f / 1024.0f));
  #pragma unroll
  for (int m = 0; m < JTAP; ++m) {
    if (t - m >= 0) acc = fmaf(w[m], up[t - m] * (1.0f / 1024.0f), acc);
  }
  y[i] = acc;
}

// Phase 3: out[b][t][hid] = spike_bit + y[b][t]   (pure stream write)
// grid = B_SZ*SEQ/8 blocks, 256 threads; each block does 8 timesteps x 1024 hid.
__global__ __launch_bounds__(256) void out_kernel(const unsigned long long* __restrict__ spk,
                                                  const float* __restrict__ y,
                                                  float4* __restrict__ out) {
  const int bt8  = blockIdx.x;          // 0..B_SZ*SEQ/8-1
  const int b    = bt8 >> 9;            // 512 t-groups per batch
  const int tg   = bt8 & 511;
  const int lane = threadIdx.x;         // hid = 4*lane
  const int wv   = lane >> 4;
  const int sh   = (lane & 15) * 4;
  #pragma unroll
  for (int k = 0; k < 8; ++k) {
    const int t = tg * 8 + k;
    const unsigned long long m = spk[(size_t)(b * 16 + wv) * SEQ + t];
    const float yv = y[b * SEQ + t];
    float4 o;
    o.x = ((m >> (sh + 0)) & 1ull) ? 1.0f + yv : yv;
    o.y = ((m >> (sh + 1)) & 1ull) ? 1.0f + yv : yv;
    o.z = ((m >> (sh + 2)) & 1ull) ? 1.0f + yv : yv;
    o.w = ((m >> (sh + 3)) & 1ull) ? 1.0f + yv : yv;
    out[(size_t)(b * SEQ + t) * 256 + lane] = o;
  }
}

extern "C" void kernel_launch(void* const* d_in, const int* in_sizes, int n_in,
                              void* d_out, int out_size, void* d_ws, size_t ws_size,
                              hipStream_t stream) {
  const float* x  = (const float*)d_in[0];   // (8, 4096, 1024)
  const float* A  = (const float*)d_in[1];   // (64, 64)
  const float* Bv = (const float*)d_in[2];   // (64, 1)
  const float* Cv = (const float*)d_in[3];   // (1, 64)
  const float* Dp = (const float*)d_in[4];   // (1, 1)
  float* out = (float*)d_out;

  char* ws = (char*)d_ws;
  unsigned int*       ucnt = (unsigned int*)(ws + UOFF);
  float*              y    = (float*)(ws + YOFF);
  float*              w    = (float*)(ws + WOFF);
  unsigned long long* spk  = (unsigned long long*)(ws + SOFF);

  // ucnt must be zero (harness poisons ws with 0xAA before every launch)
  hipMemsetAsync(ucnt, 0, B_SZ * SEQ * sizeof(unsigned int), stream);

  w_kernel<<<1, 64, 0, stream>>>(A, Bv, Cv, w);

  dim3 g1(HID / 256, B_SZ, NCH);
  snn_kernel<<<g1, 256, 0, stream>>>(x, spk, ucnt);

  y_kernel<<<(B_SZ * SEQ) / 256, 256, 0, stream>>>(ucnt, w, Dp, y);

  out_kernel<<<(B_SZ * SEQ) / 8, 256, 0, stream>>>(spk, y, (float4*)out);
}

// Round 2
// 283.274 us; speedup vs baseline: 1.3128x; 1.3128x over previous
//
#include <hip/hip_runtime.h>
#include <cstdint>
#include <cstddef>

#define B_SZ   8
#define SEQ    4096
#define HID    1024
#define NCH    16        // time chunks
#define CHUNK  256       // SEQ / NCH
#define WARM   320       // warm-up steps (multiple of 32)
#define JTAP   16        // truncated SSM impulse-response taps

// ws layout (bytes)
#define YOFF   (131072)                 // float  y[B_SZ*SEQ]         = 128 KB
#define WOFF   (262144)                 // float  w[JTAP]
#define SOFF   (262656)                 // u64    spk[B_SZ*16*SEQ]    = 4 MB

__device__ __forceinline__ void snn_step(float& v, float& r, float xv, bool& s) {
  // match reference rounding: separate mul + add (no FMA contraction)
  v = __fadd_rn(__fmul_rn(v, 0.9f), xv);
  s = (r <= 0.0f) && (v >= 1.0f);
  v = s ? 0.0f : v;
  r = s ? 5.0f : fmaxf(r - 1.0f, 0.0f);
}

// Phase 1: LIF neuron scan, chunked in time with warm-up. No atomics, no
// per-step stores: ballot masks are collected into lanes 0..15 and stored as
// one coalesced 128B burst per 16 steps. Double-buffered x prefetch.
// grid = (HID/256, B_SZ, NCH), block = 256
__global__ __launch_bounds__(256) void snn_kernel(const float* __restrict__ x,
                                                  unsigned long long* __restrict__ spk) {
  const int hid  = blockIdx.x * 256 + threadIdx.x;
  const int b    = blockIdx.y;
  const int c    = blockIdx.z;
  const int lane = threadIdx.x & 63;
  const int wv   = hid >> 6;                 // global wave-of-hid index 0..15
  const int t0   = c * CHUNK;
  const int t1   = t0 + CHUNK;
  const int tw   = (t0 >= WARM) ? (t0 - WARM) : 0;   // chunk 0/1 start exact at t=0
  const float* __restrict__ xp = x + (size_t)(b * SEQ) * HID + hid;
  unsigned long long* __restrict__ sp = spk + (size_t)(b * 16 + wv) * SEQ;

  float v = 0.0f, r = 0.0f;
  float xa[16], xb[16];

  #pragma unroll
  for (int k = 0; k < 16; ++k) xa[k] = xp[(size_t)(tw + k) * HID];

  for (int t = tw; t < t1; t += 32) {
    // prefetch second half-batch
    #pragma unroll
    for (int k = 0; k < 16; ++k) xb[k] = xp[(size_t)(t + 16 + k) * HID];

    // process xa @ t  (emit iff past warm-up; wave-uniform branch)
    if (t >= t0) {
      unsigned long long my = 0;
      #pragma unroll
      for (int k = 0; k < 16; ++k) {
        bool s; snn_step(v, r, xa[k], s);
        unsigned long long m = __ballot(s);
        if ((lane & 15) == k) my = m;
      }
      if (lane < 16) sp[t + lane] = my;      // 128B coalesced burst
    } else {
      #pragma unroll
      for (int k = 0; k < 16; ++k) { bool s; snn_step(v, r, xa[k], s); }
    }

    // prefetch next first half-batch
    if (t + 32 < t1) {
      #pragma unroll
      for (int k = 0; k < 16; ++k) xa[k] = xp[(size_t)(t + 32 + k) * HID];
    }

    // process xb @ t+16
    if (t + 16 >= t0) {
      unsigned long long my = 0;
      #pragma unroll
      for (int k = 0; k < 16; ++k) {
        bool s; snn_step(v, r, xb[k], s);
        unsigned long long m = __ballot(s);
        if ((lane & 15) == k) my = m;
      }
      if (lane < 16) sp[t + 16 + lane] = my;
    } else {
      #pragma unroll
      for (int k = 0; k < 16; ++k) { bool s; snn_step(v, r, xb[k], s); }
    }
  }
}

// Phase 0: w_m = C . A^m . B  via Krylov iteration. 1 wave.
__global__ void w_kernel(const float* __restrict__ A, const float* __restrict__ Bv,
                         const float* __restrict__ Cv, float* __restrict__ w) {
  const int lane = threadIdx.x;  // 0..63
  float arow[64];
  #pragma unroll 8
  for (int s = 0; s < 64; ++s) arow[s] = A[lane * 64 + s];
  float p = Bv[lane];
  float cv = Cv[lane];
  for (int m = 0; m < JTAP; ++m) {
    float t = cv * p;
    #pragma unroll
    for (int off = 32; off; off >>= 1) t += __shfl_xor(t, off);
    if (lane == 0) w[m] = t;
    float np = 0.0f;
    #pragma unroll 8
    for (int s = 0; s < 64; ++s) np = fmaf(arow[s], __shfl(p, s), np);
    p = np;
  }
}

// Phase 2: u from spk popcounts (LDS tile), then y[b][t] = D*u_t + sum w_m u_{t-m}
// grid = (SEQ/256, B_SZ), block = 256
__global__ __launch_bounds__(256) void y_kernel(const unsigned long long* __restrict__ spk,
                                                const float* __restrict__ w,
                                                const float* __restrict__ Dp,
                                                float* __restrict__ y) {
  __shared__ float su[CHUNK + JTAP];   // u for t0-16 .. t0+255
  __shared__ float ws[JTAP];
  const int tid = threadIdx.x;
  const int b   = blockIdx.y;
  const int t0  = blockIdx.x * 256;
  const unsigned long long* __restrict__ sb = spk + (size_t)b * 16 * SEQ;

  if (tid < JTAP) ws[tid] = w[tid];
  {
    const int t = t0 + tid;
    int cc = 0;
    #pragma unroll
    for (int wv = 0; wv < 16; ++wv) cc += __popcll(sb[(size_t)wv * SEQ + t]);
    su[JTAP + tid] = cc * (1.0f / 1024.0f);
  }
  if (tid < JTAP) {
    const int t = t0 - JTAP + tid;
    int cc = 0;
    if (t >= 0) {
      #pragma unroll
      for (int wv = 0; wv < 16; ++wv) cc += __popcll(sb[(size_t)wv * SEQ + t]);
    }
    su[tid] = (t >= 0) ? cc * (1.0f / 1024.0f) : 0.0f;
  }
  __syncthreads();

  const float u = su[JTAP + tid];
  float acc = Dp[0] * u;
  #pragma unroll
  for (int m = 0; m < JTAP; ++m) acc = fmaf(ws[m], su[JTAP + tid - m], acc);
  y[b * SEQ + t0 + tid] = acc;
}

// Phase 3: out[b][t][hid] = spike_bit + y[b][t]   (pure stream write)
// grid = B_SZ*SEQ/8 blocks, 256 threads; each block does 8 timesteps x 1024 hid.
__global__ __launch_bounds__(256) void out_kernel(const unsigned long long* __restrict__ spk,
                                                  const float* __restrict__ y,
                                                  float4* __restrict__ out) {
  const int bt8  = blockIdx.x;          // 0..B_SZ*SEQ/8-1
  const int b    = bt8 >> 9;            // 512 t-groups per batch
  const int tg   = bt8 & 511;
  const int lane = threadIdx.x;         // hid = 4*lane
  const int wv   = lane >> 4;
  const int sh   = (lane & 15) * 4;
  #pragma unroll
  for (int k = 0; k < 8; ++k) {
    const int t = tg * 8 + k;
    const unsigned long long m = spk[(size_t)(b * 16 + wv) * SEQ + t];
    const float yv = y[b * SEQ + t];
    float4 o;
    o.x = ((m >> (sh + 0)) & 1ull) ? 1.0f + yv : yv;
    o.y = ((m >> (sh + 1)) & 1ull) ? 1.0f + yv : yv;
    o.z = ((m >> (sh + 2)) & 1ull) ? 1.0f + yv : yv;
    o.w = ((m >> (sh + 3)) & 1ull) ? 1.0f + yv : yv;
    out[(size_t)(b * SEQ + t) * 256 + lane] = o;
  }
}

extern "C" void kernel_launch(void* const* d_in, const int* in_sizes, int n_in,
                              void* d_out, int out_size, void* d_ws, size_t ws_size,
                              hipStream_t stream) {
  const float* x  = (const float*)d_in[0];   // (8, 4096, 1024)
  const float* A  = (const float*)d_in[1];   // (64, 64)
  const float* Bv = (const float*)d_in[2];   // (64, 1)
  const float* Cv = (const float*)d_in[3];   // (1, 64)
  const float* Dp = (const float*)d_in[4];   // (1, 1)
  float* out = (float*)d_out;

  char* ws = (char*)d_ws;
  float*              y   = (float*)(ws + YOFF);
  float*              w   = (float*)(ws + WOFF);
  unsigned long long* spk = (unsigned long long*)(ws + SOFF);

  w_kernel<<<1, 64, 0, stream>>>(A, Bv, Cv, w);

  dim3 g1(HID / 256, B_SZ, NCH);
  snn_kernel<<<g1, 256, 0, stream>>>(x, spk);

  dim3 g2(SEQ / 256, B_SZ);
  y_kernel<<<g2, 256, 0, stream>>>(spk, w, Dp, y);

  out_kernel<<<(B_SZ * SEQ) / 8, 256, 0, stream>>>(spk, y, (float4*)out);
}